// Round 8
// baseline (13677.814 us; speedup 1.0000x reference)
//
#include <hip/hip_runtime.h>
#include <stdint.h>

// B=256,T=512,H=256,4 layers. 8 groups x MB=32 rows. Cell (g,l) = one B-WG
// (recurrence: streams W_hh bf16 from L2, h lives in own LDS, pointwise in-reg)
// + one A-WG for l>=1 (x-projection: streams W_ih, ships fp32 gate partials
// incl. biases via L3 with >=1-tick pipeline slack). No critical-path L3 RT.
#define T_ 512
#define H_ 256
#define MB 32
#define NBUF 4
#define HSLOT 8192      // shorts per h image (16 frag-rows x 512)
#define GSLOT 32768     // floats per gx slot (1024 gates x 32 m)
#define WMAT  262144    // elements per 1024x256 weight matrix

typedef __attribute__((ext_vector_type(8))) short  short8;
typedef __attribute__((ext_vector_type(4))) float  floatx4;
typedef unsigned long long ull;

struct Params {
  const float* x;
  const float* Wih[4]; const float* Whh[4]; const float* bih[4]; const float* bhh[4];
  const float* fcW; const float* fcb;
  short* whh_bf;  // [4][1024][256] bf16 (prep kernel)
  short* wih_bf;  // [3][1024][256] bf16, layers 1..3
  int*   fB;      // 32 cells x 32 ints (flag at [0], 128B line): fB=t <=> h(t-1) in ring
  int*   fA;      // 24 acells x 32 ints: fA=t+1 <=> gx(t) in ring
  short* hring;   // [32][NBUF][HSLOT] h images (A-fragment layout)
  float* gxring;  // [24][NBUF][GSLOT] fp32 gate partials (bias included)
};

__device__ __forceinline__ short f2bf(float f){
  uint32_t u = __builtin_bit_cast(uint32_t, f);
  u += 0x7fffu + ((u >> 16) & 1u);
  return (short)(u >> 16);
}
__device__ __forceinline__ float bf2f(short s){
  uint32_t u = ((uint32_t)(uint16_t)s) << 16;
  return __builtin_bit_cast(float, u);
}
__device__ __forceinline__ float sigm(float v){ return 1.0f / (1.0f + __expf(-v)); }
__device__ __forceinline__ float tanh_(float v){
  float a = fabsf(v);
  float e = __expf(-2.0f * a);
  float r = (1.0f - e) / (1.0f + e);
  return v < 0.0f ? -r : r;
}

// Proven L3-coherent exchange (r2/r5/r6/r7): relaxed agent-scope atomics.
__device__ __forceinline__ ull a_ld64(const ull* p){
  return __hip_atomic_load(p, __ATOMIC_RELAXED, __HIP_MEMORY_SCOPE_AGENT);
}
__device__ __forceinline__ void a_st64(ull* p, ull v){
  __hip_atomic_store(p, v, __ATOMIC_RELAXED, __HIP_MEMORY_SCOPE_AGENT);
}
__device__ __forceinline__ int a_ldi(const int* p){
  return __hip_atomic_load(p, __ATOMIC_RELAXED, __HIP_MEMORY_SCOPE_AGENT);
}
__device__ __forceinline__ void a_sti(int* p, int v){
  __hip_atomic_store(p, v, __ATOMIC_RELAXED, __HIP_MEMORY_SCOPE_AGENT);
}

#define MFMA(a,b,c) __builtin_amdgcn_mfma_f32_16x16x32_bf16((a),(b),(c),0,0,0)

__device__ __forceinline__ void wpoll(const int* p, int thr, bool& dead){
  if (dead) return;
  int guard = 0;
  for (;;){
    int v = a_ldi(p);
    if (__all((int)(v >= thr))) break;
    if (++guard > (1 << 17)) { dead = true; break; }
  }
}

// ---- B-WG: recurrence owner for cell (g,l). 512 threads = 8 waves. --------
// Wave w owns h-dims [w*32, w*32+32) x 4 gates = 128 gate rows; nt = gate*2+j2.
template<bool L0>
__device__ __forceinline__ void run_B(const Params& p, int g, int l, short* a_frag){
  const int tid = threadIdx.x, lane = tid & 63, wave = tid >> 6;
  const int n15 = lane & 15, q4 = lane >> 4;
  const int cell = l * 8 + g;

  int* fB_self = p.fB + cell * 32;
  int* fA_self = L0 ? fB_self : p.fA + ((l - 1) * 8 + g) * 32;
  int* fA_down = (l < 3) ? p.fA + (l * 8 + g) * 32 : fB_self;
  short* hr = p.hring + (size_t)cell * NBUF * HSLOT;
  const float* gxr = L0 ? (const float*)nullptr
                        : p.gxring + (size_t)((l - 1) * 8 + g) * NBUF * GSLOT;
  const short* wbase = p.whh_bf + (size_t)l * WMAT;

  // per-lane weight offsets (shorts) for its 8 nt
  int woff[8];
  float bv[8], wv[8];
  #pragma unroll
  for (int nt = 0; nt < 8; ++nt){
    int grow = (nt >> 1) * 256 + wave * 32 + (nt & 1) * 16 + n15;  // gate*256+dim
    woff[nt] = grow * 256 + q4 * 8;
    if (L0){ bv[nt] = p.bih[0][grow] + p.bhh[0][grow]; wv[nt] = p.Wih[0][grow]; }
  }

  // zero both LDS A-fragment buffers (h(-1) = 0)
  { ull* z = (ull*)a_frag + tid * 8;
    #pragma unroll
    for (int i = 0; i < 8; ++i) z[i] = 0ull; }
  __syncthreads();

  float cst[16];
  #pragma unroll
  for (int i = 0; i < 16; ++i) cst[i] = 0.f;

  // wave-0 poll map: lanes 0-7 gx ready (l>0); lanes 8-15 down-throttle (l<3)
  const int* pp; int dlt;
  if (lane < 8)      { pp = L0 ? fB_self : fA_self; dlt = L0 ? -1000000 : 1; }
  else if (lane < 16){ pp = (l < 3) ? fA_down : fB_self; dlt = (l < 3) ? -3 : -1000000; }
  else               { pp = fB_self; dlt = -1000000; }
  bool dead = false;

  for (int t = 0; t < T_; ++t){
    short* frag_rd = a_frag + (t & 1) * HSLOT;          // h(t-1)
    short* frag_wr = a_frag + ((t + 1) & 1) * HSLOT;    // h(t)

    if (wave == 0) wpoll(pp, t + dlt, dead);
    __syncthreads();

    short8 wf[2][8];
    #pragma unroll
    for (int nt = 0; nt < 8; ++nt)
      wf[0][nt] = *(const short8*)(wbase + woff[nt]);   // kb = 0

    ull gv[32];
    float xv[8];
    floatx4 acc[8][2];
    #pragma unroll
    for (int nt = 0; nt < 8; ++nt){
      acc[nt][0] = floatx4{0.f,0.f,0.f,0.f};
      acc[nt][1] = floatx4{0.f,0.f,0.f,0.f};
    }

    #pragma unroll
    for (int kb = 0; kb < 8; ++kb){
      if (kb < 7){
        #pragma unroll
        for (int nt = 0; nt < 8; ++nt)
          wf[(kb + 1) & 1][nt] = *(const short8*)(wbase + woff[nt] + (kb + 1) * 32);
      }
      if (kb == 4){
        if (!L0){
          const ull* gb = (const ull*)(gxr + (size_t)(t & 3) * GSLOT);
          #pragma unroll
          for (int nt = 0; nt < 8; ++nt)
            #pragma unroll
            for (int mt = 0; mt < 2; ++mt){
              const ull* gp = gb + ((wave * 8 + nt) * 2 + mt) * 128 + lane * 2;
              gv[(nt * 2 + mt) * 2]     = a_ld64(gp);
              gv[(nt * 2 + mt) * 2 + 1] = a_ld64(gp + 1);
            }
        } else {
          #pragma unroll
          for (int mt = 0; mt < 2; ++mt)
            #pragma unroll
            for (int r = 0; r < 4; ++r)
              xv[mt * 4 + r] = p.x[(size_t)(g * MB + mt * 16 + q4 * 4 + r) * T_ + t];
        }
      }
      short8 a0 = *(const short8*)&frag_rd[(kb * 2 + 0) * 512 + lane * 8];
      short8 a1 = *(const short8*)&frag_rd[(kb * 2 + 1) * 512 + lane * 8];
      #pragma unroll
      for (int nt = 0; nt < 8; ++nt){
        acc[nt][0] = MFMA(a0, wf[kb & 1][nt], acc[nt][0]);
        acc[nt][1] = MFMA(a1, wf[kb & 1][nt], acc[nt][1]);
      }
    }

    // deferred h(t-1) publish -> ring slot (t-1)&3 (stores drain by tick end)
    if (t > 0){
      const ull* hs = (const ull*)frag_rd + tid * 4;
      ull* hd = (ull*)(hr + (size_t)((t - 1) & 3) * HSLOT) + tid * 4;
      #pragma unroll
      for (int i = 0; i < 4; ++i) a_st64(hd + i, hs[i]);
    }

    // fold gx (l>0) or bias + x*W_ih0 (l=0)
    if (!L0){
      #pragma unroll
      for (int nt = 0; nt < 8; ++nt)
        #pragma unroll
        for (int mt = 0; mt < 2; ++mt){
          float2 lo = __builtin_bit_cast(float2, gv[(nt * 2 + mt) * 2]);
          float2 hi = __builtin_bit_cast(float2, gv[(nt * 2 + mt) * 2 + 1]);
          acc[nt][mt][0] += lo.x; acc[nt][mt][1] += lo.y;
          acc[nt][mt][2] += hi.x; acc[nt][mt][3] += hi.y;
        }
    } else {
      #pragma unroll
      for (int nt = 0; nt < 8; ++nt)
        #pragma unroll
        for (int mt = 0; mt < 2; ++mt)
          #pragma unroll
          for (int r = 0; r < 4; ++r)
            acc[nt][mt][r] += bv[nt] + xv[mt * 4 + r] * wv[nt];
    }

    // pointwise in-register: lane owns dims {wave*32 + j2*16 + n15}, m = mt*16+q4*4+r
    #pragma unroll
    for (int j2 = 0; j2 < 2; ++j2)
      #pragma unroll
      for (int mt = 0; mt < 2; ++mt)
        #pragma unroll
        for (int r = 0; r < 4; ++r){
          float gi = acc[0 + j2][mt][r];
          float gf = acc[2 + j2][mt][r];
          float gg = acc[4 + j2][mt][r];
          float go = acc[6 + j2][mt][r];
          float iv = sigm(gi), fv = sigm(gf), gt = tanh_(gg), ov = sigm(go);
          float c = fv * cst[(j2 * 2 + mt) * 4 + r] + iv * gt;
          cst[(j2 * 2 + mt) * 4 + r] = c;
          float h = ov * tanh_(c);
          frag_wr[(wave * 2 + mt) * 512 +
                  ((j2 * 2 + (n15 >> 3)) * 16 + q4 * 4 + r) * 8 + (n15 & 7)] = f2bf(h);
        }

    __builtin_amdgcn_s_waitcnt(0);
    __syncthreads();
    if (tid == 0 && t > 0) a_sti(fB_self, t);
  }

  // epilogue: publish h(T-1) (sits in buffer (T_&1) = 0)
  {
    const ull* hs = (const ull*)(a_frag + (T_ & 1) * HSLOT) + tid * 4;
    ull* hd = (ull*)(hr + (size_t)((T_ - 1) & 3) * HSLOT) + tid * 4;
    #pragma unroll
    for (int i = 0; i < 4; ++i) a_st64(hd + i, hs[i]);
    __builtin_amdgcn_s_waitcnt(0);
    __syncthreads();
    if (tid == 0) a_sti(fB_self, T_);
  }
}

// ---- A-WG: x-projection for cell (g,l), l>=1 ------------------------------
__device__ __forceinline__ void run_A(const Params& p, int g, int l, short* a_frag){
  const int tid = threadIdx.x, lane = tid & 63, wave = tid >> 6;
  const int n15 = lane & 15, q4 = lane >> 4;
  const int acell = (l - 1) * 8 + g;

  int* fB_up   = p.fB + ((l - 1) * 8 + g) * 32;
  int* fB_self = p.fB + (l * 8 + g) * 32;
  int* fA_self = p.fA + acell * 32;
  const short* hr_up = p.hring + (size_t)((l - 1) * 8 + g) * NBUF * HSLOT;
  float* gxr = p.gxring + (size_t)acell * NBUF * GSLOT;
  const short* wbase = p.wih_bf + (size_t)(l - 1) * WMAT;

  int woff[8];
  float bv[8];
  #pragma unroll
  for (int nt = 0; nt < 8; ++nt){
    int grow = (nt >> 1) * 256 + wave * 32 + (nt & 1) * 16 + n15;
    woff[nt] = grow * 256 + q4 * 8;
    bv[nt] = p.bih[l][grow] + p.bhh[l][grow];
  }

  const int* pp; int dlt;
  if (lane < 8)      { pp = fB_up;   dlt = 1; }    // h_up(t) ready
  else if (lane < 16){ pp = fB_self; dlt = -3; }   // gx-ring overwrite throttle
  else               { pp = fA_self; dlt = -1000000; }
  bool dead = false;

  for (int t = 0; t < T_; ++t){
    if (wave == 0) wpoll(pp, t + dlt, dead);
    __syncthreads();

    // stage x(t) = h_up(t) image -> LDS
    {
      const ull* sp = (const ull*)hr_up + (size_t)(t & 3) * (HSLOT / 4) + tid * 4;
      ull v0 = a_ld64(sp), v1 = a_ld64(sp + 1), v2 = a_ld64(sp + 2), v3 = a_ld64(sp + 3);
      ull* dp = (ull*)a_frag + tid * 4;
      dp[0] = v0; dp[1] = v1; dp[2] = v2; dp[3] = v3;
    }
    __syncthreads();

    short8 wf[2][8];
    #pragma unroll
    for (int nt = 0; nt < 8; ++nt)
      wf[0][nt] = *(const short8*)(wbase + woff[nt]);

    floatx4 acc[8][2];
    #pragma unroll
    for (int nt = 0; nt < 8; ++nt){
      acc[nt][0] = floatx4{bv[nt], bv[nt], bv[nt], bv[nt]};
      acc[nt][1] = floatx4{bv[nt], bv[nt], bv[nt], bv[nt]};
    }

    #pragma unroll
    for (int kb = 0; kb < 8; ++kb){
      if (kb < 7){
        #pragma unroll
        for (int nt = 0; nt < 8; ++nt)
          wf[(kb + 1) & 1][nt] = *(const short8*)(wbase + woff[nt] + (kb + 1) * 32);
      }
      short8 a0 = *(const short8*)&a_frag[(kb * 2 + 0) * 512 + lane * 8];
      short8 a1 = *(const short8*)&a_frag[(kb * 2 + 1) * 512 + lane * 8];
      #pragma unroll
      for (int nt = 0; nt < 8; ++nt){
        acc[nt][0] = MFMA(a0, wf[kb & 1][nt], acc[nt][0]);
        acc[nt][1] = MFMA(a1, wf[kb & 1][nt], acc[nt][1]);
      }
    }

    // ship fp32 partials (lane-linear; B uses identical mapping)
    {
      ull* gb = (ull*)(gxr + (size_t)(t & 3) * GSLOT);
      #pragma unroll
      for (int nt = 0; nt < 8; ++nt)
        #pragma unroll
        for (int mt = 0; mt < 2; ++mt){
          ull* gp = gb + ((wave * 8 + nt) * 2 + mt) * 128 + lane * 2;
          float2 lo{acc[nt][mt][0], acc[nt][mt][1]};
          float2 hi{acc[nt][mt][2], acc[nt][mt][3]};
          a_st64(gp,     __builtin_bit_cast(ull, lo));
          a_st64(gp + 1, __builtin_bit_cast(ull, hi));
        }
    }
    __builtin_amdgcn_s_waitcnt(0);
    __syncthreads();
    if (tid == 0) a_sti(fA_self, t + 1);
  }
}

__global__ __launch_bounds__(512, 2) void lstm_kernel(Params p){
  __shared__ short a_frag[2 * HSLOT];   // 32 KB
  const int bid = blockIdx.x;
  if (bid < 32){
    int l = bid >> 3, g = bid & 7;
    if (l == 0) run_B<true >(p, g, 0, a_frag);
    else        run_B<false>(p, g, l, a_frag);
  } else {
    int idx = bid - 32;
    run_A(p, idx & 7, (idx >> 3) + 1, a_frag);
  }
}

// one-time (per launch) fp32 -> bf16 weight conversion
__global__ void prep_kernel(Params p){
  int bid = blockIdx.x;                 // 7168 = 7 x 1024
  int mi = bid >> 10, row = bid & 1023;
  const float* src = (mi < 4) ? p.Whh[mi] : p.Wih[mi - 3];
  short* dst = (mi < 4) ? p.whh_bf + (size_t)mi * WMAT
                        : p.wih_bf + (size_t)(mi - 4) * WMAT;
  int c = threadIdx.x * 4;              // 64 threads x 4 elems
  float4 v = *(const float4*)(src + (size_t)row * 256 + c);
  ull o = (ull)(uint16_t)f2bf(v.x)
        | ((ull)(uint16_t)f2bf(v.y) << 16)
        | ((ull)(uint16_t)f2bf(v.z) << 32)
        | ((ull)(uint16_t)f2bf(v.w) << 48);
  *(ull*)(dst + (size_t)row * 256 + c) = o;
}

// FC on h_3(T-1): decode A-fragment image, cell (3,g), ring slot 3
__global__ void fc_kernel(const short* __restrict__ hring, const float* __restrict__ fcW,
                          const float* __restrict__ fcb, float* __restrict__ out){
  int b = blockIdx.x, lane = threadIdx.x;
  int g = b >> 5, m = b & 31;
  int mt = m >> 4, mm = m & 15;
  const short* base = hring + (size_t)(24 + g) * NBUF * HSLOT
                    + (size_t)((T_ - 1) & 3) * HSLOT;
  float s = 0.f;
  #pragma unroll
  for (int k = 0; k < 4; ++k){
    int d = lane + 64 * k;
    int kb = d >> 5, koff = d & 31;
    short hv = base[(kb * 2 + mt) * 512 + ((koff >> 3) * 16 + mm) * 8 + (koff & 7)];
    s += bf2f(hv) * fcW[d];
  }
  #pragma unroll
  for (int off = 32; off; off >>= 1) s += __shfl_down(s, off);
  if (lane == 0) out[b] = s + fcb[0];
}

extern "C" void kernel_launch(void* const* d_in, const int* in_sizes, int n_in,
                              void* d_out, int out_size, void* d_ws, size_t ws_size,
                              hipStream_t stream) {
  Params P;
  P.x = (const float*)d_in[0];
  for (int l = 0; l < 4; ++l){
    P.Wih[l] = (const float*)d_in[1 + 4*l];
    P.Whh[l] = (const float*)d_in[2 + 4*l];
    P.bih[l] = (const float*)d_in[3 + 4*l];
    P.bhh[l] = (const float*)d_in[4 + 4*l];
  }
  P.fcW = (const float*)d_in[17];
  P.fcb = (const float*)d_in[18];

  char* ws = (char*)d_ws;
  const size_t MB1 = 1u << 20;
  P.fB     = (int*)ws;                           // 4 KB
  P.fA     = (int*)(ws + 4096);                  // 3 KB
  P.whh_bf = (short*)(ws + 16384);               // 2 MB
  P.wih_bf = (short*)(ws + 16384 + 2 * MB1);     // 1.5 MB
  P.hring  = (short*)(ws + 4 * MB1);             // 2 MB
  P.gxring = (float*)(ws + 8 * MB1);             // 12 MB

  hipMemsetAsync(ws, 0, 8192, stream);
  hipLaunchKernelGGL(prep_kernel, dim3(7168), dim3(64), 0, stream, P);
  hipLaunchKernelGGL(lstm_kernel, dim3(56), dim3(512), 0, stream, P);
  hipLaunchKernelGGL(fc_kernel, dim3(256), dim3(64), 0, stream,
                     P.hring, P.fcW, P.fcb, (float*)d_out);
}

// Round 9
// 2788.629 us; speedup vs baseline: 4.9049x; 4.9049x over previous
//
#include <hip/hip_runtime.h>
#include <stdint.h>

// B=256,T=512,H=256,4 layers. r6 skeleton (8 groups x MB=32, 4 layers x 8 slices,
// weights in VGPRs, L3 agent-scope exchange) with merged single poll, register
// x(t+1) prefetch, and fragment-image ring (identity staging).
#define T_ 512
#define H_ 256
#define MB 32
#define NBUF 8
#define ISLOT 8192     // shorts per h image: 16 frag rows x 512 (16 KB)
#define NWG 256        // 8 groups x 4 layers x 8 slices

typedef __attribute__((ext_vector_type(8))) short  short8;
typedef __attribute__((ext_vector_type(4))) float  floatx4;
typedef unsigned long long ull;

struct Params {
  const float* x;
  const float* Wih[4]; const float* Whh[4]; const float* bih[4]; const float* bhh[4];
  const float* fcW; const float* fcb;
  int*   flags;   // [8g][4l][32 ints]: one 128B line per (g,l); [slice] = ticks done
  short* hring;   // [8g][4l][NBUF][ISLOT] h images (exact A-fragment layout)
};

__device__ __forceinline__ short f2bf(float f){
  uint32_t u = __builtin_bit_cast(uint32_t, f);
  u += 0x7fffu + ((u >> 16) & 1u);          // RNE
  return (short)(u >> 16);
}
__device__ __forceinline__ float bf2f(short s){
  uint32_t u = ((uint32_t)(uint16_t)s) << 16;
  return __builtin_bit_cast(float, u);
}
__device__ __forceinline__ float sigm(float v){ return 1.0f / (1.0f + __expf(-v)); }
__device__ __forceinline__ float tanh_(float v){
  float a = fabsf(v);
  float e = __expf(-2.0f * a);
  float r = (1.0f - e) / (1.0f + e);
  return v < 0.0f ? -r : r;
}

// Proven L3-coherent exchange (r2/r5/r6): relaxed agent-scope atomics.
__device__ __forceinline__ ull a_ld64(const ull* p){
  return __hip_atomic_load(p, __ATOMIC_RELAXED, __HIP_MEMORY_SCOPE_AGENT);
}
__device__ __forceinline__ void a_st32(unsigned* p, unsigned v){
  __hip_atomic_store(p, v, __ATOMIC_RELAXED, __HIP_MEMORY_SCOPE_AGENT);
}
__device__ __forceinline__ int a_ldi(const int* p){
  return __hip_atomic_load(p, __ATOMIC_RELAXED, __HIP_MEMORY_SCOPE_AGENT);
}
__device__ __forceinline__ void a_sti(int* p, int v){
  __hip_atomic_store(p, v, __ATOMIC_RELAXED, __HIP_MEMORY_SCOPE_AGENT);
}

#define MFMA(a,b,c) __builtin_amdgcn_mfma_f32_16x16x32_bf16((a),(b),(c),0,0,0)

__device__ __forceinline__ void wpoll(const int* p, int thr, bool& dead){
  if (dead) return;
  int guard = 0;
  for (;;){
    int v = a_ldi(p);
    if (__all((int)(v >= thr))) break;
    if (++guard > (1 << 16)) { dead = true; break; }
  }
}

template<bool L0>
__device__ __forceinline__ void run_cell(const Params& p, int g, int l, int slice,
    short* a_frag, float (*g_lds)[MB][33], float (*bias_lds)[32],
    float (*wih0_lds)[32], float* x0_lds)
{
  constexpr int KBT = L0 ? 8 : 16;
  const int tid = threadIdx.x, lane = tid & 63, wave = tid >> 6;  // wave = gate
  const int n15 = lane & 15, q4 = lane >> 4;

  int* fl_self = p.flags + (g * 4 + l) * 32;
  int* fl_up   = L0 ? fl_self : fl_self - 32;
  int* fl_down = (l < 3) ? fl_self + 32 : fl_self;
  short* hr_self = p.hring + (size_t)((g * 4 + l) * NBUF) * ISLOT;
  const short* hr_up = L0 ? (const short*)nullptr
                          : hr_self - (size_t)NBUF * ISLOT;

  if (tid < 128){
    int gt = tid >> 5, j = tid & 31;
    int gr = gt * 256 + slice * 32 + j;
    bias_lds[gt][j] = p.bih[l][gr] + p.bhh[l][gr];
    if (L0) wih0_lds[gt][j] = p.Wih[0][gr];    // W_ih0 is [1024 x 1]
  }

  // ---- Weight B-fragments resident in VGPRs (r6-proven mapping) ----
  short8 wf0[KBT], wf1[KBT];
  const int g0 = wave * 256 + slice * 32 + n15;   // N-tile 0 gate row
  const int g1 = g0 + 16;                         // N-tile 1
  #pragma unroll
  for (int kb = 0; kb < KBT; ++kb){
    const float* base; int kk;
    if (L0)          { base = p.Whh[0]; kk = kb * 32 + q4 * 8; }
    else if (kb < 8) { base = p.Wih[l]; kk = kb * 32 + q4 * 8; }
    else             { base = p.Whh[l]; kk = (kb - 8) * 32 + q4 * 8; }
    const float* p0 = base + (size_t)g0 * H_ + kk;
    const float* p1 = base + (size_t)g1 * H_ + kk;
    short8 a, b;
    #pragma unroll
    for (int i = 0; i < 8; ++i){ a[i] = f2bf(p0[i]); b[i] = f2bf(p1[i]); }
    wf0[kb] = a; wf1[kb] = b;
  }

  // zero whole LDS fragment buffer (h(-1) = 0)
  { ull* z = (ull*)a_frag + tid * 16;
    #pragma unroll
    for (int i = 0; i < 16; ++i) z[i] = 0ull; }

  float c00 = 0.f, c01 = 0.f, c10 = 0.f, c11 = 0.f;
  const int r0 = (tid >> 4) * 2, r1 = r0 + 1;   // batch rows (r0 even → same mt)
  const int pc = (tid & 15) * 2;                // h cols within slice

  // merged poll map (ALL waves poll; each self-releases):
  //  lanes 0-7: siblings >= t ; 8-15: upstream >= min(t+2,T) ; 16-23: down >= t-7
  const int* pp; int dlt;
  if (lane < 8)      { pp = fl_self + lane; dlt = 0; }
  else if (lane < 16){ if (L0){ pp = fl_self; dlt = -1000000; }
                       else   { pp = fl_up + (lane - 8); dlt = 2; } }
  else if (lane < 24){ if (l < 3){ pp = fl_down + (lane - 16); dlt = -7; }
                       else      { pp = fl_self; dlt = -1000000; } }
  else               { pp = fl_self + (lane & 7); dlt = -1000000; }
  bool dead = false;

  // ---- Prologue: prefetch x(0) ----
  ull px[8];
  float xcur = 0.f;
  if (!L0){
    wpoll(fl_up + (lane & 7), 1, dead);          // upstream h(0) published
    const ull* s = (const ull*)hr_up + tid * 8;  // slot 0
    #pragma unroll
    for (int i = 0; i < 8; ++i) px[i] = a_ld64(s + i);
  } else if (wave == 0 && lane < MB){
    xcur = p.x[(size_t)(g * MB + lane) * T_];
  }
  __syncthreads();

  for (int t = 0; t < T_; ++t){
    // ---- single merged poll ----
    { int thr = t + dlt; if (thr > T_) thr = T_;
      wpoll(pp, thr, dead); }

    // ---- stage: x from prefetch regs; h(t-1) from ring (identity copy) ----
    if (!L0){
      ull* d = (ull*)a_frag + tid * 8;           // x rows 0..15
      #pragma unroll
      for (int i = 0; i < 8; ++i) d[i] = px[i];
    } else if (wave == 0 && lane < MB){
      x0_lds[lane] = xcur;
    }
    if (t > 0){
      const ull* s = (const ull*)(hr_self + (size_t)((t - 1) & 7) * ISLOT) + tid * 8;
      ull hv[8];
      #pragma unroll
      for (int i = 0; i < 8; ++i) hv[i] = a_ld64(s + i);
      ull* d = (ull*)a_frag + (L0 ? 0 : 2048) + tid * 8;   // h rows
      #pragma unroll
      for (int i = 0; i < 8; ++i) d[i] = hv[i];
    }
    // ---- issue x(t+1) prefetch (pending until end-of-tick waitcnt) ----
    if (!L0){
      if (t + 1 < T_){
        const ull* s = (const ull*)(hr_up + (size_t)((t + 1) & 7) * ISLOT) + tid * 8;
        #pragma unroll
        for (int i = 0; i < 8; ++i) px[i] = a_ld64(s + i);
      }
    } else if (wave == 0 && lane < MB && t + 1 < T_){
      xcur = p.x[(size_t)(g * MB + lane) * T_ + (t + 1)];
    }
    __syncthreads();

    // ---- MFMA: kb 0..KBT-1 (x part 0..7 for l>0, h part rest), r6-proven ----
    floatx4 acc[2][2][2] = {};
    #pragma unroll
    for (int kb = 0; kb < KBT; ++kb){
      #pragma unroll
      for (int mt = 0; mt < 2; ++mt){
        short8 af = *(short8*)&a_frag[(kb * 2 + mt) * 512 + lane * 8];
        int pr = kb & 1;
        acc[mt][0][pr] = MFMA(af, wf0[kb], acc[mt][0][pr]);
        acc[mt][1][pr] = MFMA(af, wf1[kb], acc[mt][1][pr]);
      }
    }
    #pragma unroll
    for (int mt = 0; mt < 2; ++mt){
      floatx4 s0 = acc[mt][0][0] + acc[mt][0][1];
      floatx4 s1 = acc[mt][1][0] + acc[mt][1][1];
      int mrow = mt * 16 + q4 * 4;
      #pragma unroll
      for (int r = 0; r < 4; ++r){
        g_lds[wave][mrow + r][n15]      = s0[r];
        g_lds[wave][mrow + r][16 + n15] = s1[r];
      }
    }
    __syncthreads();

    // ---- pointwise (r6-proven) -> packed u32 into fragment-image ring ----
    {
      float xs0 = 0.f, xs1 = 0.f;
      if (L0){ xs0 = x0_lds[r0]; xs1 = x0_lds[r1]; }
      short* slot = hr_self + (size_t)(t & 7) * ISLOT;
      #pragma unroll
      for (int rr = 0; rr < 2; ++rr){
        const int row = rr ? r1 : r0;
        const float xs = rr ? xs1 : xs0;
        float gi0 = g_lds[0][row][pc]   + bias_lds[0][pc];
        float gi1 = g_lds[0][row][pc+1] + bias_lds[0][pc+1];
        float gf0 = g_lds[1][row][pc]   + bias_lds[1][pc];
        float gf1 = g_lds[1][row][pc+1] + bias_lds[1][pc+1];
        float gg0 = g_lds[2][row][pc]   + bias_lds[2][pc];
        float gg1 = g_lds[2][row][pc+1] + bias_lds[2][pc+1];
        float go0 = g_lds[3][row][pc]   + bias_lds[3][pc];
        float go1 = g_lds[3][row][pc+1] + bias_lds[3][pc+1];
        if (L0){
          gi0 += xs * wih0_lds[0][pc]; gi1 += xs * wih0_lds[0][pc+1];
          gf0 += xs * wih0_lds[1][pc]; gf1 += xs * wih0_lds[1][pc+1];
          gg0 += xs * wih0_lds[2][pc]; gg1 += xs * wih0_lds[2][pc+1];
          go0 += xs * wih0_lds[3][pc]; go1 += xs * wih0_lds[3][pc+1];
        }
        float i0 = sigm(gi0), i1 = sigm(gi1);
        float f0 = sigm(gf0), f1 = sigm(gf1);
        float gv0 = tanh_(gg0), gv1 = tanh_(gg1);
        float o0 = sigm(go0), o1 = sigm(go1);
        float& ca = rr ? c10 : c00;
        float& cb = rr ? c11 : c01;
        ca = f0 * ca + i0 * gv0;
        cb = f1 * cb + i1 * gv1;
        float h0 = o0 * tanh_(ca);
        float h1 = o1 * tanh_(cb);
        unsigned pk = (unsigned)(uint16_t)f2bf(h0) | ((unsigned)(uint16_t)f2bf(h1) << 16);
        // image coords: kb=slice, mt=row>>4, lane8=(pc>>3)*16+(row&15), i=pc&7
        unsigned off = (unsigned)((slice * 2 + (row >> 4)) * 512
                     + ((pc >> 3) * 16 + (row & 15)) * 8 + (pc & 7));
        a_st32((unsigned*)(slot + off), pk);
      }
    }

    // ---- drain (h stores + x prefetch), then publish ----
    __asm__ volatile("" ::: "memory");
    __builtin_amdgcn_s_waitcnt(0);
    __asm__ volatile("" ::: "memory");
    __syncthreads();
    if (tid == 0) a_sti(fl_self + slice, t + 1);
  }
}

__global__ __launch_bounds__(256, 1) void lstm_kernel(Params p){
  __shared__ short a_frag[32 * 512];          // 32 KB (x rows 0..15, h rows 16..31)
  __shared__ float g_lds[4][MB][33];
  __shared__ float bias_lds[4][32];
  __shared__ float wih0_lds[4][32];
  __shared__ float x0_lds[MB];

  const int wg    = blockIdx.x;
  const int g     = wg >> 5;
  const int l     = (wg >> 3) & 3;
  const int slice = wg & 7;
  if (l == 0) run_cell<true >(p, g, 0, slice, a_frag, g_lds, bias_lds, wih0_lds, x0_lds);
  else        run_cell<false>(p, g, l, slice, a_frag, g_lds, bias_lds, wih0_lds, x0_lds);
}

// FC on h_3(T-1): decode fragment image, cell (g,3), ring slot (T-1)&7 = 7
__global__ void fc_kernel(const short* __restrict__ hring, const float* __restrict__ fcW,
                          const float* __restrict__ fcb, float* __restrict__ out){
  int b = blockIdx.x, lane = threadIdx.x;
  int g = b >> 5, m = b & 31;
  int mt = m >> 4, mm = m & 15;
  const short* base = hring + (size_t)((g * 4 + 3) * NBUF + ((T_ - 1) & 7)) * ISLOT;
  float s = 0.f;
  #pragma unroll
  for (int k = 0; k < 4; ++k){
    int d = lane + 64 * k;
    int kb = d >> 5, koff = d & 31;
    short hv = base[(kb * 2 + mt) * 512 + ((koff >> 3) * 16 + mm) * 8 + (koff & 7)];
    s += bf2f(hv) * fcW[d];
  }
  #pragma unroll
  for (int off = 32; off; off >>= 1) s += __shfl_down(s, off);
  if (lane == 0) out[b] = s + fcb[0];
}

extern "C" void kernel_launch(void* const* d_in, const int* in_sizes, int n_in,
                              void* d_out, int out_size, void* d_ws, size_t ws_size,
                              hipStream_t stream) {
  Params P;
  P.x = (const float*)d_in[0];
  for (int l = 0; l < 4; ++l){
    P.Wih[l] = (const float*)d_in[1 + 4*l];
    P.Whh[l] = (const float*)d_in[2 + 4*l];
    P.bih[l] = (const float*)d_in[3 + 4*l];
    P.bhh[l] = (const float*)d_in[4 + 4*l];
  }
  P.fcW = (const float*)d_in[17];
  P.fcb = (const float*)d_in[18];

  char* ws = (char*)d_ws;
  P.flags = (int*)ws;                        // 32 lines x 128 B = 4 KB
  P.hring = (short*)(ws + 16384);            // 32 x 8 x 16 KB = 4 MB

  hipMemsetAsync(ws, 0, 8192, stream);
  hipLaunchKernelGGL(lstm_kernel, dim3(NWG), dim3(256), 0, stream, P);
  hipLaunchKernelGGL(fc_kernel, dim3(256), dim3(64), 0, stream,
                     P.hring, P.fcW, P.fcb, (float*)d_out);
}

// Round 10
// 1957.511 us; speedup vs baseline: 6.9874x; 1.4246x over previous
//
#include <hip/hip_runtime.h>
#include <stdint.h>

// B=256,T=512,H=256,4 layers. 8 groups x MB=32, 4 layers x 8 slices, weights in
// VGPRs, L3 agent-scope exchange (proven r2/r5/r6/r9). Round 10: raw s_barrier +
// manual waitcnt (no implicit full drains), conflict-free lane-contiguous staging,
// issue-ordered vmcnt(4) to land h loads while x(t+1) prefetch stays in flight.
#define T_ 512
#define H_ 256
#define MB 32
#define NBUF 8
#define ISLOT 8192     // shorts per h image: 16 frag rows x 512 (16 KB)
#define NWG 256

typedef __attribute__((ext_vector_type(8))) short  short8;
typedef __attribute__((ext_vector_type(4))) float  floatx4;
typedef __attribute__((ext_vector_type(4))) unsigned int uint4v;
typedef unsigned long long ull;

struct Params {
  const float* x;
  const float* Wih[4]; const float* Whh[4]; const float* bih[4]; const float* bhh[4];
  const float* fcW; const float* fcb;
  int*   flags;   // [8g][4l][32 ints], one 128B line per (g,l); [slice] = ticks done
  short* hring;   // [8g][4l][NBUF][ISLOT] h images (exact A-fragment layout)
};

__device__ __forceinline__ short f2bf(float f){
  uint32_t u = __builtin_bit_cast(uint32_t, f);
  u += 0x7fffu + ((u >> 16) & 1u);          // RNE
  return (short)(u >> 16);
}
__device__ __forceinline__ float bf2f(short s){
  uint32_t u = ((uint32_t)(uint16_t)s) << 16;
  return __builtin_bit_cast(float, u);
}
__device__ __forceinline__ float sigm(float v){ return 1.0f / (1.0f + __expf(-v)); }
__device__ __forceinline__ float tanh_(float v){
  float a = fabsf(v);
  float e = __expf(-2.0f * a);
  float r = (1.0f - e) / (1.0f + e);
  return v < 0.0f ? -r : r;
}

__device__ __forceinline__ void a_st32(unsigned* p, unsigned v){
  __hip_atomic_store(p, v, __ATOMIC_RELAXED, __HIP_MEMORY_SCOPE_AGENT);
}
__device__ __forceinline__ int a_ldi(const int* p){
  return __hip_atomic_load(p, __ATOMIC_RELAXED, __HIP_MEMORY_SCOPE_AGENT);
}
__device__ __forceinline__ void a_sti(int* p, int v){
  __hip_atomic_store(p, v, __ATOMIC_RELAXED, __HIP_MEMORY_SCOPE_AGENT);
}
// L3-coherent 16B load (same sc0 sc1 path __hip_atomic lowers to; volatile asm
// preserves issue order so vmcnt(N) counts are exact).
__device__ __forceinline__ void ld16(uint4v& d, const void* p){
  asm volatile("global_load_dwordx4 %0, %1, off sc0 sc1" : "=v"(d) : "v"(p));
}
__device__ __forceinline__ void ldf32(float& d, const void* p){
  asm volatile("global_load_dword %0, %1, off" : "=v"(d) : "v"(p));
}
template<int N> __device__ __forceinline__ void waitvm(){
  if constexpr (N == 0) asm volatile("s_waitcnt vmcnt(0)" ::: "memory");
  else if constexpr (N == 1) asm volatile("s_waitcnt vmcnt(1)" ::: "memory");
  else                       asm volatile("s_waitcnt vmcnt(4)" ::: "memory");
}
__device__ __forceinline__ void bar_lds(){   // LDS-visibility barrier, VM ops keep flying
  asm volatile("s_waitcnt lgkmcnt(0)" ::: "memory");
  __builtin_amdgcn_s_barrier();
}
__device__ __forceinline__ void bar_only(){
  __builtin_amdgcn_s_barrier();
}

#define MFMA(a,b,c) __builtin_amdgcn_mfma_f32_16x16x32_bf16((a),(b),(c),0,0,0)

__device__ __forceinline__ void wpoll(const int* p, int thr, bool& dead){
  if (dead) return;
  int guard = 0;
  for (;;){
    int v = a_ldi(p);
    if (__all((int)(v >= thr))) break;
    if (++guard > (1 << 16)) { dead = true; break; }
  }
}

template<bool L0>
__device__ __forceinline__ void run_cell(const Params& p, int g, int l, int slice,
    short* a_frag, float (*g_lds)[MB][33], float (*bias_lds)[32],
    float (*wih0_lds)[32], float* x0_lds)
{
  constexpr int KBT = L0 ? 8 : 16;
  const int tid = threadIdx.x, lane = tid & 63, wave = tid >> 6;  // wave = gate
  const int n15 = lane & 15, q4 = lane >> 4;

  int* fl_self = p.flags + (g * 4 + l) * 32;
  int* fl_up   = L0 ? fl_self : fl_self - 32;
  int* fl_down = (l < 3) ? fl_self + 32 : fl_self;
  short* hr_self = p.hring + (size_t)((g * 4 + l) * NBUF) * ISLOT;
  const short* hr_up = L0 ? (const short*)nullptr
                          : hr_self - (size_t)NBUF * ISLOT;

  if (tid < 128){
    int gt = tid >> 5, j = tid & 31;
    int gr = gt * 256 + slice * 32 + j;
    bias_lds[gt][j] = p.bih[l][gr] + p.bhh[l][gr];
    if (L0) wih0_lds[gt][j] = p.Wih[0][gr];    // W_ih0 is [1024 x 1]
  }

  // ---- Weight B-fragments resident in VGPRs (r6/r9-proven mapping) ----
  short8 wf0[KBT], wf1[KBT];
  const int g0 = wave * 256 + slice * 32 + n15;
  const int g1 = g0 + 16;
  #pragma unroll
  for (int kb = 0; kb < KBT; ++kb){
    const float* base; int kk;
    if (L0)          { base = p.Whh[0]; kk = kb * 32 + q4 * 8; }
    else if (kb < 8) { base = p.Wih[l]; kk = kb * 32 + q4 * 8; }
    else             { base = p.Whh[l]; kk = (kb - 8) * 32 + q4 * 8; }
    const float* p0 = base + (size_t)g0 * H_ + kk;
    const float* p1 = base + (size_t)g1 * H_ + kk;
    short8 a, b;
    #pragma unroll
    for (int i = 0; i < 8; ++i){ a[i] = f2bf(p0[i]); b[i] = f2bf(p1[i]); }
    wf0[kb] = a; wf1[kb] = b;
  }

  float c00 = 0.f, c01 = 0.f, c10 = 0.f, c11 = 0.f;
  const int r0 = (tid >> 4) * 2, r1 = r0 + 1;
  const int pc = (tid & 15) * 2;

  // merged poll map (all waves poll; lanes 0-7 siblings>=t, 8-15 up>=t+2, 16-23 down>=t-7)
  const int* pp; int dlt;
  if (lane < 8)      { pp = fl_self + lane; dlt = 0; }
  else if (lane < 16){ if (L0){ pp = fl_self; dlt = -1000000; }
                       else   { pp = fl_up + (lane - 8); dlt = 2; } }
  else if (lane < 24){ if (l < 3){ pp = fl_down + (lane - 16); dlt = -7; }
                       else      { pp = fl_self; dlt = -1000000; } }
  else               { pp = fl_self + (lane & 7); dlt = -1000000; }
  bool dead = false;

  uint4v* fragv = (uint4v*)a_frag;
  uint4v px[4];
  float xcur = 0.f;

  // ---- Prologue: x(0) ----
  if (!L0){
    wpoll(fl_up + (lane & 7), 1, dead);
    const char* s = (const char*)hr_up;            // slot 0
    #pragma unroll
    for (int k = 0; k < 4; ++k) ld16(px[k], s + (size_t)(k * 256 + tid) * 16);
  } else if (wave == 0 && lane < MB){
    ldf32(xcur, &p.x[(size_t)(g * MB + lane) * T_]);
  }
  waitvm<0>();
  __syncthreads();

  for (int t = 0; t < T_; ++t){
    { int thr = t + dlt; if (thr > T_) thr = T_;
      wpoll(pp, thr, dead); }

    // phase 1: stage x (lane-contiguous, conflict-free)
    if (!L0){
      #pragma unroll
      for (int k = 0; k < 4; ++k) fragv[k * 256 + tid] = px[k];
    } else if (wave == 0 && lane < MB){
      x0_lds[lane] = xcur;
    }

    // phase 2: issue h(t-1) loads, THEN x(t+1) prefetch (order fixes vmcnt counts)
    uint4v hv[4];
    const bool havh = (t > 0);
    const bool pf = (t + 1 < T_);
    if (havh){
      const char* s = (const char*)(hr_self + (size_t)((t - 1) & 7) * ISLOT);
      #pragma unroll
      for (int k = 0; k < 4; ++k) ld16(hv[k], s + (size_t)(k * 256 + tid) * 16);
    }
    if (!L0){
      if (pf){
        const char* s = (const char*)(hr_up + (size_t)((t + 1) & 7) * ISLOT);
        #pragma unroll
        for (int k = 0; k < 4; ++k) ld16(px[k], s + (size_t)(k * 256 + tid) * 16);
      }
    } else if (wave == 0 && lane < MB && pf){
      ldf32(xcur, &p.x[(size_t)(g * MB + lane) * T_ + (t + 1)]);
    }

    bar_lds();   // bar1: x rows / x0_lds visible; h + px loads still in flight

    floatx4 acc[2][2][2] = {};
    if (!L0){
      // x-part MFMA (kb 0..7) hides part of the h-load RT
      #pragma unroll
      for (int kb = 0; kb < 8; ++kb){
        #pragma unroll
        for (int mt = 0; mt < 2; ++mt){
          short8 af = *(short8*)&a_frag[(kb * 2 + mt) * 512 + lane * 8];
          int pr = kb & 1;
          acc[mt][0][pr] = MFMA(af, wf0[kb], acc[mt][0][pr]);
          acc[mt][1][pr] = MFMA(af, wf1[kb], acc[mt][1][pr]);
        }
      }
    }

    // phase 5: land h rows (vmcnt(4) leaves the 4 px prefetch loads in flight)
    if (!L0){ if (pf) waitvm<4>(); else waitvm<0>(); }
    else    { if (wave == 0 && pf) waitvm<1>(); else waitvm<0>(); }
    {
      const int hbase = L0 ? 0 : 1024;            // u128 index of h region
      if (havh){
        #pragma unroll
        for (int k = 0; k < 4; ++k) fragv[hbase + k * 256 + tid] = hv[k];
      } else {
        uint4v z = {0, 0, 0, 0};
        #pragma unroll
        for (int k = 0; k < 4; ++k) fragv[hbase + k * 256 + tid] = z;
      }
    }
    bar_lds();   // bar2: h rows visible

    // h-part MFMA
    #pragma unroll
    for (int kb = (L0 ? 0 : 8); kb < KBT; ++kb){
      #pragma unroll
      for (int mt = 0; mt < 2; ++mt){
        short8 af = *(short8*)&a_frag[(kb * 2 + mt) * 512 + lane * 8];
        int pr = kb & 1;
        acc[mt][0][pr] = MFMA(af, wf0[kb], acc[mt][0][pr]);
        acc[mt][1][pr] = MFMA(af, wf1[kb], acc[mt][1][pr]);
      }
    }
    #pragma unroll
    for (int mt = 0; mt < 2; ++mt){
      floatx4 s0 = acc[mt][0][0] + acc[mt][0][1];
      floatx4 s1 = acc[mt][1][0] + acc[mt][1][1];
      int mrow = mt * 16 + q4 * 4;
      #pragma unroll
      for (int r = 0; r < 4; ++r){
        g_lds[wave][mrow + r][n15]      = s0[r];
        g_lds[wave][mrow + r][16 + n15] = s1[r];
      }
    }
    bar_lds();   // bar3: gates visible

    // pointwise -> packed u32 into fragment-image ring (r9-proven mapping)
    {
      float xs0 = 0.f, xs1 = 0.f;
      if (L0){ xs0 = x0_lds[r0]; xs1 = x0_lds[r1]; }
      short* slot = hr_self + (size_t)(t & 7) * ISLOT;
      #pragma unroll
      for (int rr = 0; rr < 2; ++rr){
        const int row = rr ? r1 : r0;
        const float xs = rr ? xs1 : xs0;
        float gi0 = g_lds[0][row][pc]   + bias_lds[0][pc];
        float gi1 = g_lds[0][row][pc+1] + bias_lds[0][pc+1];
        float gf0 = g_lds[1][row][pc]   + bias_lds[1][pc];
        float gf1 = g_lds[1][row][pc+1] + bias_lds[1][pc+1];
        float gg0 = g_lds[2][row][pc]   + bias_lds[2][pc];
        float gg1 = g_lds[2][row][pc+1] + bias_lds[2][pc+1];
        float go0 = g_lds[3][row][pc]   + bias_lds[3][pc];
        float go1 = g_lds[3][row][pc+1] + bias_lds[3][pc+1];
        if (L0){
          gi0 += xs * wih0_lds[0][pc]; gi1 += xs * wih0_lds[0][pc+1];
          gf0 += xs * wih0_lds[1][pc]; gf1 += xs * wih0_lds[1][pc+1];
          gg0 += xs * wih0_lds[2][pc]; gg1 += xs * wih0_lds[2][pc+1];
          go0 += xs * wih0_lds[3][pc]; go1 += xs * wih0_lds[3][pc+1];
        }
        float i0 = sigm(gi0), i1 = sigm(gi1);
        float f0 = sigm(gf0), f1 = sigm(gf1);
        float gv0 = tanh_(gg0), gv1 = tanh_(gg1);
        float o0 = sigm(go0), o1 = sigm(go1);
        float& ca = rr ? c10 : c00;
        float& cb = rr ? c11 : c01;
        ca = f0 * ca + i0 * gv0;
        cb = f1 * cb + i1 * gv1;
        float h0 = o0 * tanh_(ca);
        float h1 = o1 * tanh_(cb);
        unsigned pk = (unsigned)(uint16_t)f2bf(h0) | ((unsigned)(uint16_t)f2bf(h1) << 16);
        unsigned off = (unsigned)((slice * 2 + (row >> 4)) * 512
                     + ((pc >> 3) * 16 + (row & 15)) * 8 + (pc & 7));
        a_st32((unsigned*)(slot + off), pk);
      }
    }

    // bar4: h stores drained (px prefetch issued ~1us ago -> already complete)
    waitvm<0>();
    bar_only();
    if (tid == 0) a_sti(fl_self + slice, t + 1);
  }
}

__global__ __launch_bounds__(256, 1) void lstm_kernel(Params p){
  __shared__ short a_frag[32 * 512];          // 32 KB (x rows 0..15, h rows 16..31)
  __shared__ float g_lds[4][MB][33];
  __shared__ float bias_lds[4][32];
  __shared__ float wih0_lds[4][32];
  __shared__ float x0_lds[MB];

  const int wg    = blockIdx.x;
  const int g     = wg >> 5;
  const int l     = (wg >> 3) & 3;
  const int slice = wg & 7;
  if (l == 0) run_cell<true >(p, g, 0, slice, a_frag, g_lds, bias_lds, wih0_lds, x0_lds);
  else        run_cell<false>(p, g, l, slice, a_frag, g_lds, bias_lds, wih0_lds, x0_lds);
}

// FC on h_3(T-1): decode fragment image, cell (g,3), ring slot (T-1)&7 = 7
__global__ void fc_kernel(const short* __restrict__ hring, const float* __restrict__ fcW,
                          const float* __restrict__ fcb, float* __restrict__ out){
  int b = blockIdx.x, lane = threadIdx.x;
  int g = b >> 5, m = b & 31;
  int mt = m >> 4, mm = m & 15;
  const short* base = hring + (size_t)((g * 4 + 3) * NBUF + ((T_ - 1) & 7)) * ISLOT;
  float s = 0.f;
  #pragma unroll
  for (int k = 0; k < 4; ++k){
    int d = lane + 64 * k;
    int kb = d >> 5, koff = d & 31;
    short hv = base[(kb * 2 + mt) * 512 + ((koff >> 3) * 16 + mm) * 8 + (koff & 7)];
    s += bf2f(hv) * fcW[d];
  }
  #pragma unroll
  for (int off = 32; off; off >>= 1) s += __shfl_down(s, off);
  if (lane == 0) out[b] = s + fcb[0];
}

extern "C" void kernel_launch(void* const* d_in, const int* in_sizes, int n_in,
                              void* d_out, int out_size, void* d_ws, size_t ws_size,
                              hipStream_t stream) {
  Params P;
  P.x = (const float*)d_in[0];
  for (int l = 0; l < 4; ++l){
    P.Wih[l] = (const float*)d_in[1 + 4*l];
    P.Whh[l] = (const float*)d_in[2 + 4*l];
    P.bih[l] = (const float*)d_in[3 + 4*l];
    P.bhh[l] = (const float*)d_in[4 + 4*l];
  }
  P.fcW = (const float*)d_in[17];
  P.fcb = (const float*)d_in[18];

  char* ws = (char*)d_ws;
  P.flags = (int*)ws;                        // 32 lines x 128 B = 4 KB
  P.hring = (short*)(ws + 16384);            // 32 x 8 x 16 KB = 4 MB

  hipMemsetAsync(ws, 0, 8192, stream);
  hipLaunchKernelGGL(lstm_kernel, dim3(NWG), dim3(256), 0, stream, P);
  hipLaunchKernelGGL(fc_kernel, dim3(256), dim3(64), 0, stream,
                     P.hring, P.fcW, P.fcb, (float*)d_out);
}